// Round 3
// baseline (325.966 us; speedup 1.0000x reference)
//
#include <hip/hip_runtime.h>
#include <math.h>

#define N_NODES 2048
#define N_EDGES 65536
#define SEQL 5
#define IN_F 32
#define HID 64
#define OUT_F 16
#define LN_EPS 1e-5f
#define CAP 128   // fixed slot capacity per node; in-degree ~ Poisson(32), P(>128) ~ e^-200

// ===== K1: edge slot-scatter (1 int + 1 float atomic per edge) + weight premultiply =====
__global__ __launch_bounds__(256) void k_build(
        const int* __restrict__ ei, const float* __restrict__ ew,
        const float* __restrict__ Wcz, const float* __restrict__ Wlz,
        const float* __restrict__ bcz, const float* __restrict__ blz,
        const float* __restrict__ Wch, const float* __restrict__ Wlh,
        const float* __restrict__ bch, const float* __restrict__ blh,
        float* __restrict__ deg, int* __restrict__ cnt, float2* __restrict__ cedge,
        float* __restrict__ Wzp, float* __restrict__ Whp, float* __restrict__ bUV){
    int b = blockIdx.x, t = threadIdx.x;
    if (b < 256){
        int e = b * 256 + t;
        int s = ei[e], d = ei[N_EDGES + e];
        float wv = ew[e];
        atomicAdd(&deg[d], wv);
        int pos = atomicAdd(&cnt[d], 1);
        if (pos < CAP){
            float2 v;
            v.x = __int_as_float(s);
            v.y = wv;                          // raw weight; dinv folded at gather time
            cedge[(d << 7) + pos] = v;
        }
    } else {
        const float* Wc = (b == 256) ? Wcz : Wch;
        const float* Wl = (b == 256) ? Wlz : Wlh;
        const float* bc = (b == 256) ? bcz : bch;
        const float* bl = (b == 256) ? blz : blh;
        float* Wp = (b == 256) ? Wzp : Whp;
        for (int idx = t; idx < IN_F*HID; idx += 256){
            int i = idx >> 6, f = idx & 63;
            float s = 0.f;
            #pragma unroll 8
            for (int k = 0; k < HID; ++k) s += Wc[i*HID+k] * Wl[k*HID+f];
            Wp[idx] = s;
        }
        if (t < HID){
            float s = bl[t];
            for (int k = 0; k < HID; ++k) s += bc[k] * Wl[k*HID+t];
            bUV[(b-256)*HID + t] = s;
        }
    }
}

// ===== K2: gate pipeline, wave-per-node, barrier-free, no LDS =====
// 512 blocks x 256 threads; wave w handles node n = blk*4 + w.
__global__ __launch_bounds__(256) void k_gate(const float* __restrict__ x,
        const float* __restrict__ deg, const int* __restrict__ cnt,
        const float2* __restrict__ cedge,
        const float* __restrict__ bUV, const float* __restrict__ Wzp, const float* __restrict__ Whp,
        const float* __restrict__ Wred, const float* __restrict__ bred,
        const float* __restrict__ Wi1, const float* __restrict__ bi1, const float* __restrict__ Wc1,
        float* __restrict__ ag, float* __restrict__ bjp, float* __restrict__ hw1y){
    int tid = threadIdx.x;
    int w = tid >> 6, l = tid & 63;
    int n = (blockIdx.x << 2) + w;
    int el = l >> 5, f = l & 31;               // 2 edge slots x 32 feature lanes
    int m = min(cnt[n], CAP);
    float dvn = 1.f / sqrtf(deg[n] + 1.f);
    float dsn = dvn * dvn;
    const float2* ce = cedge + (n << 7);
    // ---- gather: a_t[f] = sum_e (ew*dinv[s]) * x[t][s][f] ----
    float a0=0.f, a1=0.f, a2=0.f, a3=0.f, a4=0.f;
    for (int p = el; p < m; p += 2){
        float2 ed = ce[p];
        int s = __float_as_int(ed.x);
        float c = ed.y * (1.f / sqrtf(deg[s] + 1.f));
        a0 += c * x[(0*N_NODES + s)*IN_F + f];
        a1 += c * x[(1*N_NODES + s)*IN_F + f];
        a2 += c * x[(2*N_NODES + s)*IN_F + f];
        a3 += c * x[(3*N_NODES + s)*IN_F + f];
        a4 += c * x[(4*N_NODES + s)*IN_F + f];
    }
    a0 += __shfl_xor(a0, 32); a1 += __shfl_xor(a1, 32); a2 += __shfl_xor(a2, 32);
    a3 += __shfl_xor(a3, 32); a4 += __shfl_xor(a4, 32);
    // axs[t][f] = dsn*x[t][n][f] + dvn*a_t   (valid on all lanes; halves duplicated)
    a0 = dsn * x[(0*N_NODES + n)*IN_F + f] + dvn * a0;
    a1 = dsn * x[(1*N_NODES + n)*IN_F + f] + dvn * a1;
    a2 = dsn * x[(2*N_NODES + n)*IN_F + f] + dvn * a2;
    a3 = dsn * x[(3*N_NODES + n)*IN_F + f] + dvn * a3;
    a4 = dsn * x[(4*N_NODES + n)*IN_F + f] + dvn * a4;
    // ---- gate: zz_t/hh_t for hidden feature l, via lane broadcasts ----
    float bz = bUV[l], bh = bUV[HID + l];
    float z0=bz, z1=bz, z2=bz, z3=bz, z4=bz;
    float h0=bh, h1=bh, h2=bh, h3=bh, h4=bh;
    #pragma unroll
    for (int i = 0; i < IN_F; ++i){
        float wz = Wzp[i*HID + l];
        float wh = Whp[i*HID + l];
        float b0 = __shfl(a0, i), b1 = __shfl(a1, i), b2 = __shfl(a2, i);
        float b3 = __shfl(a3, i), b4 = __shfl(a4, i);
        z0 += b0*wz; z1 += b1*wz; z2 += b2*wz; z3 += b3*wz; z4 += b4*wz;
        h0 += b0*wh; h1 += b1*wh; h2 += b2*wh; h3 += b3*wh; h4 += b4*wh;
    }
    float s0 = 1.f/(1.f+expf(-z0)), s1 = 1.f/(1.f+expf(-z1)), s2 = 1.f/(1.f+expf(-z2));
    float s3 = 1.f/(1.f+expf(-z3)), s4 = 1.f/(1.f+expf(-z4));
    h0 = (1.f-s0)*tanhf(h0); h1 = (1.f-s1)*tanhf(h1); h2 = (1.f-s2)*tanhf(h2);
    h3 = (1.f-s3)*tanhf(h3); h4 = (1.f-s4)*tanhf(h4);
    // ---- reduce: hemb[l] = bred[l] + sum_t sum_k hs_t[k] * Wred[(t*64+k)*64+l] ----
    float pw = bred[l];
    #pragma unroll
    for (int k = 0; k < HID; ++k){
        float b0 = __shfl(h0, k), b1 = __shfl(h1, k), b2 = __shfl(h2, k);
        float b3 = __shfl(h3, k), b4 = __shfl(h4, k);
        pw += b0 * Wred[(0*HID + k)*HID + l];
        pw += b1 * Wred[(1*HID + k)*HID + l];
        pw += b2 * Wred[(2*HID + k)*HID + l];
        pw += b3 * Wred[(3*HID + k)*HID + l];
        pw += b4 * Wred[(4*HID + k)*HID + l];
    }
    // ---- 3 matvecs sharing broadcasts: ag, bjp(+bi1), hw1y(=dvn*emb@Wc1) ----
    float aA = 0.f, aB = bi1[l], aC = 0.f;
    #pragma unroll
    for (int k = 0; k < HID; ++k){
        float hb = __shfl(pw, k);
        aA += hb * Wi1[k*HID + l];
        aB += hb * Wi1[HID*HID + k*HID + l];
        aC += hb * Wc1[k*HID + l];
    }
    ag  [n*HID + l] = aA;
    bjp [n*HID + l] = aB;                      // bi1 folded in
    hw1y[n*HID + l] = dvn * aC;
}

// ===== K3: gcn1 wave-per-node (blocks 0..255) + score tiles 0..1023 =====
__global__ __launch_bounds__(512) void k_gcn1s(
        const float* __restrict__ hw1y, const float* __restrict__ deg,
        const int* __restrict__ cnt, const float2* __restrict__ cedge,
        const float* __restrict__ bc1, const float* __restrict__ g1, const float* __restrict__ be1,
        const float* __restrict__ Wc2, float* __restrict__ hw2y,
        const float* __restrict__ ag, const float* __restrict__ bjp,
        const float* __restrict__ Wi2, const float* __restrict__ bi2,
        float* __restrict__ outs){
    int blk = blockIdx.x;
    int tid = threadIdx.x;
    if (blk < 256){
        // ---- wave-per-node: no __syncthreads, no LDS in this path ----
        int w = tid >> 6, l = tid & 63;
        int n = (blk << 3) + w;
        int slot = l >> 4, fl = l & 15;
        int m = min(cnt[n], CAP);
        float dv = 1.f / sqrtf(deg[n] + 1.f);
        const float4* H4 = (const float4*)hw1y;
        float4 acc = {0.f,0.f,0.f,0.f};
        if (slot == 0) acc = H4[n*16 + fl];    // self term (hw1y pre-scaled by dinv[n])
        for (int p = slot; p < m; p += 4){
            float2 ed = cedge[(n << 7) + p];
            int s = __float_as_int(ed.x); float c = ed.y;   // hw1y pre-scaled by dinv[s]
            float4 h = H4[s*16 + fl];
            acc.x += c*h.x; acc.y += c*h.y; acc.z += c*h.z; acc.w += c*h.w;
        }
        acc.x += __shfl_xor(acc.x, 16); acc.y += __shfl_xor(acc.y, 16);
        acc.z += __shfl_xor(acc.z, 16); acc.w += __shfl_xor(acc.w, 16);
        acc.x += __shfl_xor(acc.x, 32); acc.y += __shfl_xor(acc.y, 32);
        acc.z += __shfl_xor(acc.z, 32); acc.w += __shfl_xor(acc.w, 32);
        float4 b4 = ((const float4*)bc1)[fl];
        float4 g;
        g.x = b4.x + dv*acc.x; g.y = b4.y + dv*acc.y;
        g.z = b4.z + dv*acc.z; g.w = b4.w + dv*acc.w;
        float s4 = g.x + g.y + g.z + g.w;
        s4 += __shfl_xor(s4, 1); s4 += __shfl_xor(s4, 2);
        s4 += __shfl_xor(s4, 4); s4 += __shfl_xor(s4, 8);
        float mu = s4 * (1.f/64.f);
        float4 d;
        d.x = g.x - mu; d.y = g.y - mu; d.z = g.z - mu; d.w = g.w - mu;
        float v4 = d.x*d.x + d.y*d.y + d.z*d.z + d.w*d.w;
        v4 += __shfl_xor(v4, 1); v4 += __shfl_xor(v4, 2);
        v4 += __shfl_xor(v4, 4); v4 += __shfl_xor(v4, 8);
        float rs = 1.f / sqrtf(v4 * (1.f/64.f) + LN_EPS);
        float4 gm = ((const float4*)g1)[fl], be = ((const float4*)be1)[fl];
        float4 h4;
        h4.x = fmaxf(d.x*rs*gm.x + be.x, 0.f);
        h4.y = fmaxf(d.y*rs*gm.y + be.y, 0.f);
        h4.z = fmaxf(d.z*rs*gm.z + be.z, 0.f);
        h4.w = fmaxf(d.w*rs*gm.w + be.w, 0.f);
        float o = 0.f;
        #pragma unroll 4
        for (int gk = 0; gk < 16; ++gk){
            float hb0 = __shfl(h4.x, gk);
            float hb1 = __shfl(h4.y, gk);
            float hb2 = __shfl(h4.z, gk);
            float hb3 = __shfl(h4.w, gk);
            o += hb0 * Wc2[(4*gk+0)*HID + l];
            o += hb1 * Wc2[(4*gk+1)*HID + l];
            o += hb2 * Wc2[(4*gk+2)*HID + l];
            o += hb3 * Wc2[(4*gk+3)*HID + l];
        }
        hw2y[n*HID + l] = dv * o;              // pre-scale for gcn2 gather
    } else {
        __shared__ float bs[64*65];            // score branch only
        __shared__ float wv[64];
        int tl = blk - 256;                    // tiles 0..1023
        int j0 = (tl & 31) * 64;
        int i0 = (tl >> 5) * 32;
        for (int idx = tid; idx < 4096; idx += 512){
            int jj = idx >> 6, f = idx & 63;
            bs[jj*65 + f] = bjp[(j0 + jj)*HID + f];
        }
        if (tid < 64) wv[tid] = Wi2[tid];
        __syncthreads();
        int tj = tid & 63;
        int w = __builtin_amdgcn_readfirstlane(tid >> 6);   // wave-uniform -> scalar a-loads
        const float* ar = ag + (i0 + w*4)*HID;
        float bi2v = bi2[0];
        float acc0 = 0.f, acc1 = 0.f, acc2 = 0.f, acc3 = 0.f;
        #pragma unroll
        for (int f = 0; f < 64; ++f){
            float bv = bs[tj*65 + f];
            float wf = wv[f];
            acc0 += fmaxf(ar[       f] + bv, 0.f) * wf;
            acc1 += fmaxf(ar[ 64 +  f] + bv, 0.f) * wf;
            acc2 += fmaxf(ar[128 +  f] + bv, 0.f) * wf;
            acc3 += fmaxf(ar[192 +  f] + bv, 0.f) * wf;
        }
        long ro = (long)(i0 + w*4) * N_NODES + j0 + tj;
        outs[ro                ] = acc0 + bi2v;
        outs[ro +     N_NODES  ] = acc1 + bi2v;
        outs[ro + 2L* N_NODES  ] = acc2 + bi2v;
        outs[ro + 3L* N_NODES  ] = acc3 + bi2v;
    }
}

// ===== K4: gcn2 wave-per-node + outp (blocks 0..255) + score tiles 1024..2047 =====
__global__ __launch_bounds__(512) void k_gcn2s(
        const float* __restrict__ hw2y, const float* __restrict__ deg,
        const int* __restrict__ cnt, const float2* __restrict__ cedge,
        const float* __restrict__ bc2, const float* __restrict__ g2, const float* __restrict__ be2,
        const float* __restrict__ Wout, const float* __restrict__ bout,
        const float* __restrict__ ag, const float* __restrict__ bjp,
        const float* __restrict__ Wi2, const float* __restrict__ bi2,
        float* __restrict__ outp, float* __restrict__ outs){
    int blk = blockIdx.x;
    int tid = threadIdx.x;
    if (blk < 256){
        int w = tid >> 6, l = tid & 63;
        int n = (blk << 3) + w;
        int slot = l >> 4, fl = l & 15;
        int m = min(cnt[n], CAP);
        float dv = 1.f / sqrtf(deg[n] + 1.f);
        const float4* H4 = (const float4*)hw2y;
        float4 acc = {0.f,0.f,0.f,0.f};
        if (slot == 0) acc = H4[n*16 + fl];
        for (int p = slot; p < m; p += 4){
            float2 ed = cedge[(n << 7) + p];
            int s = __float_as_int(ed.x); float c = ed.y;
            float4 h = H4[s*16 + fl];
            acc.x += c*h.x; acc.y += c*h.y; acc.z += c*h.z; acc.w += c*h.w;
        }
        acc.x += __shfl_xor(acc.x, 16); acc.y += __shfl_xor(acc.y, 16);
        acc.z += __shfl_xor(acc.z, 16); acc.w += __shfl_xor(acc.w, 16);
        acc.x += __shfl_xor(acc.x, 32); acc.y += __shfl_xor(acc.y, 32);
        acc.z += __shfl_xor(acc.z, 32); acc.w += __shfl_xor(acc.w, 32);
        float4 b4 = ((const float4*)bc2)[fl];
        float4 g;
        g.x = b4.x + dv*acc.x; g.y = b4.y + dv*acc.y;
        g.z = b4.z + dv*acc.z; g.w = b4.w + dv*acc.w;
        float s4 = g.x + g.y + g.z + g.w;
        s4 += __shfl_xor(s4, 1); s4 += __shfl_xor(s4, 2);
        s4 += __shfl_xor(s4, 4); s4 += __shfl_xor(s4, 8);
        float mu = s4 * (1.f/64.f);
        float4 d;
        d.x = g.x - mu; d.y = g.y - mu; d.z = g.z - mu; d.w = g.w - mu;
        float v4 = d.x*d.x + d.y*d.y + d.z*d.z + d.w*d.w;
        v4 += __shfl_xor(v4, 1); v4 += __shfl_xor(v4, 2);
        v4 += __shfl_xor(v4, 4); v4 += __shfl_xor(v4, 8);
        float rs = 1.f / sqrtf(v4 * (1.f/64.f) + LN_EPS);
        float4 gm = ((const float4*)g2)[fl], be = ((const float4*)be2)[fl];
        float4 h4;
        h4.x = fmaxf(d.x*rs*gm.x + be.x, 0.f);
        h4.y = fmaxf(d.y*rs*gm.y + be.y, 0.f);
        h4.z = fmaxf(d.z*rs*gm.z + be.z, 0.f);
        h4.w = fmaxf(d.w*rs*gm.w + be.w, 0.f);
        int f2 = l & 15;
        float o = bout[f2];
        #pragma unroll 4
        for (int gk = 0; gk < 16; ++gk){
            float hb0 = __shfl(h4.x, gk);
            float hb1 = __shfl(h4.y, gk);
            float hb2 = __shfl(h4.z, gk);
            float hb3 = __shfl(h4.w, gk);
            o += hb0 * Wout[(4*gk+0)*OUT_F + f2];
            o += hb1 * Wout[(4*gk+1)*OUT_F + f2];
            o += hb2 * Wout[(4*gk+2)*OUT_F + f2];
            o += hb3 * Wout[(4*gk+3)*OUT_F + f2];
        }
        if (slot == 0) outp[n*OUT_F + f2] = o;
    } else {
        __shared__ float bs[64*65];
        __shared__ float wv[64];
        int tl = blk - 256 + 1024;             // tiles 1024..2047
        int j0 = (tl & 31) * 64;
        int i0 = (tl >> 5) * 32;
        for (int idx = tid; idx < 4096; idx += 512){
            int jj = idx >> 6, f = idx & 63;
            bs[jj*65 + f] = bjp[(j0 + jj)*HID + f];
        }
        if (tid < 64) wv[tid] = Wi2[tid];
        __syncthreads();
        int tj = tid & 63;
        int w = __builtin_amdgcn_readfirstlane(tid >> 6);
        const float* ar = ag + (i0 + w*4)*HID;
        float bi2v = bi2[0];
        float acc0 = 0.f, acc1 = 0.f, acc2 = 0.f, acc3 = 0.f;
        #pragma unroll
        for (int f = 0; f < 64; ++f){
            float bv = bs[tj*65 + f];
            float wf = wv[f];
            acc0 += fmaxf(ar[       f] + bv, 0.f) * wf;
            acc1 += fmaxf(ar[ 64 +  f] + bv, 0.f) * wf;
            acc2 += fmaxf(ar[128 +  f] + bv, 0.f) * wf;
            acc3 += fmaxf(ar[192 +  f] + bv, 0.f) * wf;
        }
        long ro = (long)(i0 + w*4) * N_NODES + j0 + tj;
        outs[ro                ] = acc0 + bi2v;
        outs[ro +     N_NODES  ] = acc1 + bi2v;
        outs[ro + 2L* N_NODES  ] = acc2 + bi2v;
        outs[ro + 3L* N_NODES  ] = acc3 + bi2v;
    }
}

extern "C" void kernel_launch(void* const* d_in, const int* in_sizes, int n_in,
                              void* d_out, int out_size, void* d_ws, size_t ws_size,
                              hipStream_t stream){
    const float* x   = (const float*)d_in[0];
    const float* ew  = (const float*)d_in[1];
    const float* Wcz = (const float*)d_in[2];  const float* bcz = (const float*)d_in[3];
    const float* Wlz = (const float*)d_in[4];  const float* blz = (const float*)d_in[5];
    // d_in[6..9]: Wcr/bcr/Wlr/blr — dead code (H=0 so reset gate has no effect)
    const float* Wch = (const float*)d_in[10]; const float* bch = (const float*)d_in[11];
    const float* Wlh = (const float*)d_in[12]; const float* blh = (const float*)d_in[13];
    const float* Wred= (const float*)d_in[14]; const float* bred= (const float*)d_in[15];
    const float* Wc1 = (const float*)d_in[16]; const float* bc1 = (const float*)d_in[17];
    const float* Wc2 = (const float*)d_in[18]; const float* bc2 = (const float*)d_in[19];
    const float* g1  = (const float*)d_in[20]; const float* be1 = (const float*)d_in[21];
    const float* g2  = (const float*)d_in[22]; const float* be2 = (const float*)d_in[23];
    const float* Wout= (const float*)d_in[24]; const float* bout= (const float*)d_in[25];
    const float* Wi1 = (const float*)d_in[26]; const float* bi1 = (const float*)d_in[27];
    const float* Wi2 = (const float*)d_in[28]; const float* bi2 = (const float*)d_in[29];
    const int*  ei  = (const int*)d_in[30];

    float* w = (float*)d_ws;              // float offsets, 16B aligned
    float* deg   = w;                     // 2048 floats   [memset 16 KB covers deg+cnt]
    int*   cnt   = (int*)(w + 2048);      // 2048 ints
    float2* cedge= (float2*)(w + 4096);   // 2048*128 pairs = 524288 floats [4096, 528384)
    float* Wzp   = w + 528384;            // 2048
    float* Whp   = w + 530432;            // 2048
    float* bUV   = w + 532480;            // 128
    float* ag    = w + 532608;            // 131072
    float* bjp   = w + 663680;            // 131072
    float* hw1y  = w + 794752;            // 131072  (= dinv * emb@Wc1)
    float* hw2y  = w + 925824;            // 131072  (= dinv * hsh@Wc2)

    hipMemsetAsync(deg, 0, 16384, stream);
    k_build<<<258, 256, 0, stream>>>(ei, ew, Wcz, Wlz, bcz, blz, Wch, Wlh, bch, blh,
                                     deg, cnt, cedge, Wzp, Whp, bUV);
    k_gate<<<512, 256, 0, stream>>>(x, deg, cnt, cedge, bUV, Wzp, Whp,
                                    Wred, bred, Wi1, bi1, Wc1, ag, bjp, hw1y);
    k_gcn1s<<<256 + 1024, 512, 0, stream>>>(hw1y, deg, cnt, cedge, bc1, g1, be1,
                                            Wc2, hw2y, ag, bjp, Wi2, bi2,
                                            (float*)d_out + N_NODES*OUT_F);
    k_gcn2s<<<256 + 1024, 512, 0, stream>>>(hw2y, deg, cnt, cedge, bc2, g2, be2,
                                            Wout, bout, ag, bjp, Wi2, bi2,
                                            (float*)d_out, (float*)d_out + N_NODES*OUT_F);
}

// Round 4
// 198.394 us; speedup vs baseline: 1.6430x; 1.6430x over previous
//
#include <hip/hip_runtime.h>
#include <math.h>

#define N_NODES 2048
#define N_EDGES 65536
#define SEQL 5
#define IN_F 32
#define HID 64
#define OUT_F 16
#define LN_EPS 1e-5f
#define CAP 128   // fixed slot capacity per node; in-degree ~ Poisson(32), P(>128) ~ e^-200

// ===== K1: edge slot-scatter (1 int + 1 float atomic per edge) + weight premultiply =====
__global__ __launch_bounds__(256) void k_build(
        const int* __restrict__ ei, const float* __restrict__ ew,
        const float* __restrict__ Wcz, const float* __restrict__ Wlz,
        const float* __restrict__ bcz, const float* __restrict__ blz,
        const float* __restrict__ Wch, const float* __restrict__ Wlh,
        const float* __restrict__ bch, const float* __restrict__ blh,
        float* __restrict__ deg, int* __restrict__ cnt, float2* __restrict__ cedge,
        float* __restrict__ Wzp, float* __restrict__ Whp, float* __restrict__ bUV){
    int b = blockIdx.x, t = threadIdx.x;
    if (b < 256){
        int e = b * 256 + t;
        int s = ei[e], d = ei[N_EDGES + e];
        float wv = ew[e];
        atomicAdd(&deg[d], wv);
        int pos = atomicAdd(&cnt[d], 1);
        if (pos < CAP){
            float2 v;
            v.x = __int_as_float(s);
            v.y = wv;                          // raw weight; dinv folded at gather time
            cedge[(d << 7) + pos] = v;
        }
    } else {
        const float* Wc = (b == 256) ? Wcz : Wch;
        const float* Wl = (b == 256) ? Wlz : Wlh;
        const float* bc = (b == 256) ? bcz : bch;
        const float* bl = (b == 256) ? blz : blh;
        float* Wp = (b == 256) ? Wzp : Whp;
        for (int idx = t; idx < IN_F*HID; idx += 256){
            int i = idx >> 6, f = idx & 63;
            float s = 0.f;
            #pragma unroll 8
            for (int k = 0; k < HID; ++k) s += Wc[i*HID+k] * Wl[k*HID+f];
            Wp[idx] = s;
        }
        if (t < HID){
            float s = bl[t];
            for (int k = 0; k < HID; ++k) s += bc[k] * Wl[k*HID+t];
            bUV[(b-256)*HID + t] = s;
        }
    }
}

// ===== K2: gate + reduce + emb matvecs (block-per-node, 40 slots x 8 f4-lanes) =====
__global__ __launch_bounds__(320) void k_gate(const float* __restrict__ x,
        const float* __restrict__ deg, const int* __restrict__ cnt,
        const float2* __restrict__ cedge,
        const float* __restrict__ bUV, const float* __restrict__ Wzp, const float* __restrict__ Whp,
        const float* __restrict__ Wred, const float* __restrict__ bred,
        const float* __restrict__ Wi1, const float* __restrict__ bi1, const float* __restrict__ Wc1,
        float* __restrict__ ag, float* __restrict__ bjp, float* __restrict__ hw1y){
    int n = blockIdx.x;
    int tid = threadIdx.x;
    __shared__ float part[40*SEQL*IN_F];       // 25.6 KB
    __shared__ float axs[SEQL][IN_F];
    __shared__ float hs[SEQL][HID];
    __shared__ float pw[SEQL][HID];
    __shared__ float hemb[HID];
    const int slot = tid >> 3, fl = tid & 7;   // 40 slots x 8 lanes (float4 each)
    const int f = tid & 63, t = tid >> 6;      // 5 waves for the dense phases
    int m = min(cnt[n], CAP);
    float dvn = 1.f / sqrtf(deg[n] + 1.f);
    float dsn = dvn * dvn;
    const float4* X4 = (const float4*)x;
    float4 a0 = {0,0,0,0}, a1 = {0,0,0,0}, a2 = {0,0,0,0}, a3 = {0,0,0,0}, a4 = {0,0,0,0};
    for (int p = slot; p < m; p += 40){
        float2 ed = cedge[(n << 7) + p];
        int s = __float_as_int(ed.x);
        float c = ed.y * (1.f / sqrtf(deg[s] + 1.f));   // deg is L1/L2-resident (8 KB)
        float4 x0 = X4[(0*N_NODES + s)*8 + fl];
        float4 x1 = X4[(1*N_NODES + s)*8 + fl];
        float4 x2 = X4[(2*N_NODES + s)*8 + fl];
        float4 x3 = X4[(3*N_NODES + s)*8 + fl];
        float4 x4v= X4[(4*N_NODES + s)*8 + fl];
        a0.x += c*x0.x; a0.y += c*x0.y; a0.z += c*x0.z; a0.w += c*x0.w;
        a1.x += c*x1.x; a1.y += c*x1.y; a1.z += c*x1.z; a1.w += c*x1.w;
        a2.x += c*x2.x; a2.y += c*x2.y; a2.z += c*x2.z; a2.w += c*x2.w;
        a3.x += c*x3.x; a3.y += c*x3.y; a3.z += c*x3.z; a3.w += c*x3.w;
        a4.x += c*x4v.x; a4.y += c*x4v.y; a4.z += c*x4v.z; a4.w += c*x4v.w;
    }
    *(float4*)&part[(slot*SEQL + 0)*IN_F + fl*4] = a0;
    *(float4*)&part[(slot*SEQL + 1)*IN_F + fl*4] = a1;
    *(float4*)&part[(slot*SEQL + 2)*IN_F + fl*4] = a2;
    *(float4*)&part[(slot*SEQL + 3)*IN_F + fl*4] = a3;
    *(float4*)&part[(slot*SEQL + 4)*IN_F + fl*4] = a4;
    __syncthreads();
    if (tid < SEQL*IN_F){
        int tt = tid >> 5, ff = tid & 31;
        float ps = 0.f;
        #pragma unroll 8
        for (int sl = 0; sl < 40; ++sl) ps += part[(sl*SEQL + tt)*IN_F + ff];
        axs[tt][ff] = dsn * x[(tt*N_NODES + n)*IN_F + ff] + dvn * ps;
    }
    __syncthreads();
    {   // 5 waves: gate for timestep t
        float zz = bUV[f], hh = bUV[HID + f];
        #pragma unroll
        for (int i = 0; i < IN_F; ++i){
            float a = axs[t][i];               // wave-uniform LDS broadcast
            zz += a * Wzp[i*HID + f];
            hh += a * Whp[i*HID + f];
        }
        float z = 1.f / (1.f + expf(-zz));
        hs[t][f] = (1.f - z) * tanhf(hh);
    }
    __syncthreads();
    {   float pp = 0.f;
        #pragma unroll
        for (int k = 0; k < HID; ++k) pp += hs[t][k] * Wred[(t*HID + k)*HID + f];
        pw[t][f] = pp;
    }
    __syncthreads();
    if (tid < HID){
        float hr = bred[tid];
        #pragma unroll
        for (int t2 = 0; t2 < SEQL; ++t2) hr += pw[t2][tid];
        hemb[tid] = hr;
    }
    __syncthreads();
    if (t < 3){
        const float* W = (t == 0) ? Wi1 : (t == 1) ? (Wi1 + HID*HID) : Wc1;
        float acc = (t == 1) ? bi1[f] : 0.f;
        #pragma unroll
        for (int k = 0; k < HID; ++k) acc += hemb[k] * W[k*HID + f];
        if (t == 2) acc *= dvn;                // hw1y = dinv[n] * (emb @ Wc1)
        float* O = (t == 0) ? ag : (t == 1) ? bjp : hw1y;
        O[n*HID + f] = acc;                    // bjp has bi1 folded in
    }
}

// ===== K3: gcn1 wave-per-node (blocks 0..255) + score tiles 0..1023 =====
__global__ __launch_bounds__(512) void k_gcn1s(
        const float* __restrict__ hw1y, const float* __restrict__ deg,
        const int* __restrict__ cnt, const float2* __restrict__ cedge,
        const float* __restrict__ bc1, const float* __restrict__ g1, const float* __restrict__ be1,
        const float* __restrict__ Wc2, float* __restrict__ hw2y,
        const float* __restrict__ ag, const float* __restrict__ bjp,
        const float* __restrict__ Wi2, const float* __restrict__ bi2,
        float* __restrict__ outs){
    int blk = blockIdx.x;
    int tid = threadIdx.x;
    if (blk < 256){
        // ---- wave-per-node: no __syncthreads, no LDS in this path ----
        int w = tid >> 6, l = tid & 63;
        int n = (blk << 3) + w;
        int slot = l >> 4, fl = l & 15;
        int m = min(cnt[n], CAP);
        float dv = 1.f / sqrtf(deg[n] + 1.f);
        const float4* H4 = (const float4*)hw1y;
        float4 acc = {0.f,0.f,0.f,0.f};
        if (slot == 0) acc = H4[n*16 + fl];    // self term (hw1y pre-scaled by dinv[n])
        for (int p = slot; p < m; p += 4){
            float2 ed = cedge[(n << 7) + p];
            int s = __float_as_int(ed.x); float c = ed.y;   // hw1y pre-scaled by dinv[s]
            float4 h = H4[s*16 + fl];
            acc.x += c*h.x; acc.y += c*h.y; acc.z += c*h.z; acc.w += c*h.w;
        }
        acc.x += __shfl_xor(acc.x, 16); acc.y += __shfl_xor(acc.y, 16);
        acc.z += __shfl_xor(acc.z, 16); acc.w += __shfl_xor(acc.w, 16);
        acc.x += __shfl_xor(acc.x, 32); acc.y += __shfl_xor(acc.y, 32);
        acc.z += __shfl_xor(acc.z, 32); acc.w += __shfl_xor(acc.w, 32);
        float4 b4 = ((const float4*)bc1)[fl];
        float4 g;
        g.x = b4.x + dv*acc.x; g.y = b4.y + dv*acc.y;
        g.z = b4.z + dv*acc.z; g.w = b4.w + dv*acc.w;
        float s4 = g.x + g.y + g.z + g.w;
        s4 += __shfl_xor(s4, 1); s4 += __shfl_xor(s4, 2);
        s4 += __shfl_xor(s4, 4); s4 += __shfl_xor(s4, 8);
        float mu = s4 * (1.f/64.f);
        float4 d;
        d.x = g.x - mu; d.y = g.y - mu; d.z = g.z - mu; d.w = g.w - mu;
        float v4 = d.x*d.x + d.y*d.y + d.z*d.z + d.w*d.w;
        v4 += __shfl_xor(v4, 1); v4 += __shfl_xor(v4, 2);
        v4 += __shfl_xor(v4, 4); v4 += __shfl_xor(v4, 8);
        float rs = 1.f / sqrtf(v4 * (1.f/64.f) + LN_EPS);
        float4 gm = ((const float4*)g1)[fl], be = ((const float4*)be1)[fl];
        float4 h4;
        h4.x = fmaxf(d.x*rs*gm.x + be.x, 0.f);
        h4.y = fmaxf(d.y*rs*gm.y + be.y, 0.f);
        h4.z = fmaxf(d.z*rs*gm.z + be.z, 0.f);
        h4.w = fmaxf(d.w*rs*gm.w + be.w, 0.f);
        float o = 0.f;
        #pragma unroll 4
        for (int gk = 0; gk < 16; ++gk){
            float hb0 = __shfl(h4.x, gk);
            float hb1 = __shfl(h4.y, gk);
            float hb2 = __shfl(h4.z, gk);
            float hb3 = __shfl(h4.w, gk);
            o += hb0 * Wc2[(4*gk+0)*HID + l];
            o += hb1 * Wc2[(4*gk+1)*HID + l];
            o += hb2 * Wc2[(4*gk+2)*HID + l];
            o += hb3 * Wc2[(4*gk+3)*HID + l];
        }
        hw2y[n*HID + l] = dv * o;              // pre-scale for gcn2 gather
    } else {
        __shared__ float bs[64*65];            // score branch only
        __shared__ float wv[64];
        int tl = blk - 256;                    // tiles 0..1023
        int j0 = (tl & 31) * 64;
        int i0 = (tl >> 5) * 32;
        for (int idx = tid; idx < 4096; idx += 512){
            int jj = idx >> 6, f = idx & 63;
            bs[jj*65 + f] = bjp[(j0 + jj)*HID + f];
        }
        if (tid < 64) wv[tid] = Wi2[tid];
        __syncthreads();
        int tj = tid & 63;
        int w = __builtin_amdgcn_readfirstlane(tid >> 6);   // wave-uniform -> scalar a-loads
        const float* ar = ag + (i0 + w*4)*HID;
        float bi2v = bi2[0];
        float acc0 = 0.f, acc1 = 0.f, acc2 = 0.f, acc3 = 0.f;
        #pragma unroll
        for (int f = 0; f < 64; ++f){
            float bv = bs[tj*65 + f];
            float wf = wv[f];
            acc0 += fmaxf(ar[       f] + bv, 0.f) * wf;
            acc1 += fmaxf(ar[ 64 +  f] + bv, 0.f) * wf;
            acc2 += fmaxf(ar[128 +  f] + bv, 0.f) * wf;
            acc3 += fmaxf(ar[192 +  f] + bv, 0.f) * wf;
        }
        long ro = (long)(i0 + w*4) * N_NODES + j0 + tj;
        outs[ro                ] = acc0 + bi2v;
        outs[ro +     N_NODES  ] = acc1 + bi2v;
        outs[ro + 2L* N_NODES  ] = acc2 + bi2v;
        outs[ro + 3L* N_NODES  ] = acc3 + bi2v;
    }
}

// ===== K4: gcn2 wave-per-node + outp (blocks 0..255) + score tiles 1024..2047 =====
__global__ __launch_bounds__(512) void k_gcn2s(
        const float* __restrict__ hw2y, const float* __restrict__ deg,
        const int* __restrict__ cnt, const float2* __restrict__ cedge,
        const float* __restrict__ bc2, const float* __restrict__ g2, const float* __restrict__ be2,
        const float* __restrict__ Wout, const float* __restrict__ bout,
        const float* __restrict__ ag, const float* __restrict__ bjp,
        const float* __restrict__ Wi2, const float* __restrict__ bi2,
        float* __restrict__ outp, float* __restrict__ outs){
    int blk = blockIdx.x;
    int tid = threadIdx.x;
    if (blk < 256){
        int w = tid >> 6, l = tid & 63;
        int n = (blk << 3) + w;
        int slot = l >> 4, fl = l & 15;
        int m = min(cnt[n], CAP);
        float dv = 1.f / sqrtf(deg[n] + 1.f);
        const float4* H4 = (const float4*)hw2y;
        float4 acc = {0.f,0.f,0.f,0.f};
        if (slot == 0) acc = H4[n*16 + fl];
        for (int p = slot; p < m; p += 4){
            float2 ed = cedge[(n << 7) + p];
            int s = __float_as_int(ed.x); float c = ed.y;
            float4 h = H4[s*16 + fl];
            acc.x += c*h.x; acc.y += c*h.y; acc.z += c*h.z; acc.w += c*h.w;
        }
        acc.x += __shfl_xor(acc.x, 16); acc.y += __shfl_xor(acc.y, 16);
        acc.z += __shfl_xor(acc.z, 16); acc.w += __shfl_xor(acc.w, 16);
        acc.x += __shfl_xor(acc.x, 32); acc.y += __shfl_xor(acc.y, 32);
        acc.z += __shfl_xor(acc.z, 32); acc.w += __shfl_xor(acc.w, 32);
        float4 b4 = ((const float4*)bc2)[fl];
        float4 g;
        g.x = b4.x + dv*acc.x; g.y = b4.y + dv*acc.y;
        g.z = b4.z + dv*acc.z; g.w = b4.w + dv*acc.w;
        float s4 = g.x + g.y + g.z + g.w;
        s4 += __shfl_xor(s4, 1); s4 += __shfl_xor(s4, 2);
        s4 += __shfl_xor(s4, 4); s4 += __shfl_xor(s4, 8);
        float mu = s4 * (1.f/64.f);
        float4 d;
        d.x = g.x - mu; d.y = g.y - mu; d.z = g.z - mu; d.w = g.w - mu;
        float v4 = d.x*d.x + d.y*d.y + d.z*d.z + d.w*d.w;
        v4 += __shfl_xor(v4, 1); v4 += __shfl_xor(v4, 2);
        v4 += __shfl_xor(v4, 4); v4 += __shfl_xor(v4, 8);
        float rs = 1.f / sqrtf(v4 * (1.f/64.f) + LN_EPS);
        float4 gm = ((const float4*)g2)[fl], be = ((const float4*)be2)[fl];
        float4 h4;
        h4.x = fmaxf(d.x*rs*gm.x + be.x, 0.f);
        h4.y = fmaxf(d.y*rs*gm.y + be.y, 0.f);
        h4.z = fmaxf(d.z*rs*gm.z + be.z, 0.f);
        h4.w = fmaxf(d.w*rs*gm.w + be.w, 0.f);
        int f2 = l & 15;
        float o = bout[f2];
        #pragma unroll 4
        for (int gk = 0; gk < 16; ++gk){
            float hb0 = __shfl(h4.x, gk);
            float hb1 = __shfl(h4.y, gk);
            float hb2 = __shfl(h4.z, gk);
            float hb3 = __shfl(h4.w, gk);
            o += hb0 * Wout[(4*gk+0)*OUT_F + f2];
            o += hb1 * Wout[(4*gk+1)*OUT_F + f2];
            o += hb2 * Wout[(4*gk+2)*OUT_F + f2];
            o += hb3 * Wout[(4*gk+3)*OUT_F + f2];
        }
        if (slot == 0) outp[n*OUT_F + f2] = o;
    } else {
        __shared__ float bs[64*65];
        __shared__ float wv[64];
        int tl = blk - 256 + 1024;             // tiles 1024..2047
        int j0 = (tl & 31) * 64;
        int i0 = (tl >> 5) * 32;
        for (int idx = tid; idx < 4096; idx += 512){
            int jj = idx >> 6, f = idx & 63;
            bs[jj*65 + f] = bjp[(j0 + jj)*HID + f];
        }
        if (tid < 64) wv[tid] = Wi2[tid];
        __syncthreads();
        int tj = tid & 63;
        int w = __builtin_amdgcn_readfirstlane(tid >> 6);
        const float* ar = ag + (i0 + w*4)*HID;
        float bi2v = bi2[0];
        float acc0 = 0.f, acc1 = 0.f, acc2 = 0.f, acc3 = 0.f;
        #pragma unroll
        for (int f = 0; f < 64; ++f){
            float bv = bs[tj*65 + f];
            float wf = wv[f];
            acc0 += fmaxf(ar[       f] + bv, 0.f) * wf;
            acc1 += fmaxf(ar[ 64 +  f] + bv, 0.f) * wf;
            acc2 += fmaxf(ar[128 +  f] + bv, 0.f) * wf;
            acc3 += fmaxf(ar[192 +  f] + bv, 0.f) * wf;
        }
        long ro = (long)(i0 + w*4) * N_NODES + j0 + tj;
        outs[ro                ] = acc0 + bi2v;
        outs[ro +     N_NODES  ] = acc1 + bi2v;
        outs[ro + 2L* N_NODES  ] = acc2 + bi2v;
        outs[ro + 3L* N_NODES  ] = acc3 + bi2v;
    }
}

extern "C" void kernel_launch(void* const* d_in, const int* in_sizes, int n_in,
                              void* d_out, int out_size, void* d_ws, size_t ws_size,
                              hipStream_t stream){
    const float* x   = (const float*)d_in[0];
    const float* ew  = (const float*)d_in[1];
    const float* Wcz = (const float*)d_in[2];  const float* bcz = (const float*)d_in[3];
    const float* Wlz = (const float*)d_in[4];  const float* blz = (const float*)d_in[5];
    // d_in[6..9]: Wcr/bcr/Wlr/blr — dead code (H=0 so reset gate has no effect)
    const float* Wch = (const float*)d_in[10]; const float* bch = (const float*)d_in[11];
    const float* Wlh = (const float*)d_in[12]; const float* blh = (const float*)d_in[13];
    const float* Wred= (const float*)d_in[14]; const float* bred= (const float*)d_in[15];
    const float* Wc1 = (const float*)d_in[16]; const float* bc1 = (const float*)d_in[17];
    const float* Wc2 = (const float*)d_in[18]; const float* bc2 = (const float*)d_in[19];
    const float* g1  = (const float*)d_in[20]; const float* be1 = (const float*)d_in[21];
    const float* g2  = (const float*)d_in[22]; const float* be2 = (const float*)d_in[23];
    const float* Wout= (const float*)d_in[24]; const float* bout= (const float*)d_in[25];
    const float* Wi1 = (const float*)d_in[26]; const float* bi1 = (const float*)d_in[27];
    const float* Wi2 = (const float*)d_in[28]; const float* bi2 = (const float*)d_in[29];
    const int*  ei  = (const int*)d_in[30];

    float* w = (float*)d_ws;              // float offsets, 16B aligned
    float* deg   = w;                     // 2048 floats   [memset 16 KB covers deg+cnt]
    int*   cnt   = (int*)(w + 2048);      // 2048 ints
    float2* cedge= (float2*)(w + 4096);   // 2048*128 pairs = 524288 floats [4096, 528384)
    float* Wzp   = w + 528384;            // 2048
    float* Whp   = w + 530432;            // 2048
    float* bUV   = w + 532480;            // 128
    float* ag    = w + 532608;            // 131072
    float* bjp   = w + 663680;            // 131072
    float* hw1y  = w + 794752;            // 131072  (= dinv * emb@Wc1)
    float* hw2y  = w + 925824;            // 131072  (= dinv * hsh@Wc2)

    hipMemsetAsync(deg, 0, 16384, stream);
    k_build<<<258, 256, 0, stream>>>(ei, ew, Wcz, Wlz, bcz, blz, Wch, Wlh, bch, blh,
                                     deg, cnt, cedge, Wzp, Whp, bUV);
    k_gate<<<N_NODES, 320, 0, stream>>>(x, deg, cnt, cedge, bUV, Wzp, Whp,
                                        Wred, bred, Wi1, bi1, Wc1, ag, bjp, hw1y);
    k_gcn1s<<<256 + 1024, 512, 0, stream>>>(hw1y, deg, cnt, cedge, bc1, g1, be1,
                                            Wc2, hw2y, ag, bjp, Wi2, bi2,
                                            (float*)d_out + N_NODES*OUT_F);
    k_gcn2s<<<256 + 1024, 512, 0, stream>>>(hw2y, deg, cnt, cedge, bc2, g2, be2,
                                            Wout, bout, ag, bjp, Wi2, bi2,
                                            (float*)d_out, (float*)d_out + N_NODES*OUT_F);
}